// Round 7
// baseline (613.213 us; speedup 1.0000x reference)
//
#include <hip/hip_runtime.h>
#include <stdint.h>
#include <math.h>

#define DIM 1536
#define SEQ 4096
#define HEADS 12
#define HD 128

typedef __bf16 bf16x8 __attribute__((ext_vector_type(8)));
typedef float f32x4 __attribute__((ext_vector_type(4)));

typedef __attribute__((address_space(1))) void gas_void;
typedef __attribute__((address_space(3))) void las_void;

__device__ __forceinline__ float b2f(unsigned short u) {
  union { unsigned int i; float f; } x; x.i = ((unsigned int)u) << 16; return x.f;
}
__device__ __forceinline__ unsigned short f2b(float f) {
  union { float f; unsigned int i; } x; x.f = f;
  unsigned int u = x.i;
  unsigned int r = (u + 0x7fffu + ((u >> 16) & 1u)) >> 16;  // RNE
  return (unsigned short)r;
}
// async global->LDS 16B: LDS placement is wave-uniform base + lane*16
__device__ __forceinline__ void gll16(const unsigned short* g, unsigned short* l) {
  __builtin_amdgcn_global_load_lds((gas_void*)g, (las_void*)l, 16, 0, 0);
}

// ---------------- dtype detector: flag=0 bf16 inputs, flag=1 fp32 inputs
__global__ void detect_kernel(const unsigned int* __restrict__ xw, int* flag) {
  __shared__ int cnt;
  if (threadIdx.x == 0) cnt = 0;
  __syncthreads();
  int local = 0;
  for (int i = threadIdx.x; i < 1024; i += 256) {
    unsigned int e = (xw[i] >> 7) & 0xFFu;
    if (e >= 110u && e <= 140u) local++;
  }
  atomicAdd(&cnt, local);
  __syncthreads();
  if (threadIdx.x == 0) *flag = (cnt > 512) ? 0 : 1;
}

__global__ void convert_bf16_kernel(const void* __restrict__ src,
                                    unsigned short* __restrict__ dst, int n,
                                    const int* __restrict__ flag) {
  int f = *flag;
  for (int i = blockIdx.x * blockDim.x + threadIdx.x; i < n; i += gridDim.x * blockDim.x)
    dst[i] = f ? f2b(((const float*)src)[i]) : ((const unsigned short*)src)[i];
}

__global__ void convert_w4_kernel(const void* s0, const void* s1, const void* s2, const void* s3,
                                  unsigned short* d0, unsigned short* d1,
                                  unsigned short* d2, unsigned short* d3,
                                  int n, const int* __restrict__ flag) {
  const void* s; unsigned short* d;
  switch (blockIdx.y) {
    case 0: s = s0; d = d0; break;
    case 1: s = s1; d = d1; break;
    case 2: s = s2; d = d2; break;
    default: s = s3; d = d3; break;
  }
  int f = *flag;
  for (int i = blockIdx.x * blockDim.x + threadIdx.x; i < n; i += gridDim.x * blockDim.x)
    d[i] = f ? f2b(((const float*)s)[i]) : ((const unsigned short*)s)[i];
}

__global__ void convert_v6_kernel(const void* s0, const void* s1, const void* s2,
                                  const void* s3, const void* s4, const void* s5,
                                  unsigned short* d0, unsigned short* d1, unsigned short* d2,
                                  unsigned short* d3, unsigned short* d4, unsigned short* d5,
                                  int n, const int* __restrict__ flag) {
  const void* s; unsigned short* d;
  switch (blockIdx.y) {
    case 0: s = s0; d = d0; break;
    case 1: s = s1; d = d1; break;
    case 2: s = s2; d = d2; break;
    case 3: s = s3; d = d3; break;
    case 4: s = s4; d = d4; break;
    default: s = s5; d = d5; break;
  }
  int f = *flag;
  for (int i = blockIdx.x * blockDim.x + threadIdx.x; i < n; i += gridDim.x * blockDim.x)
    d[i] = f ? f2b(((const float*)s)[i]) : ((const unsigned short*)s)[i];
}

__global__ void convert_f32_kernel(const void* __restrict__ src,
                                   float* __restrict__ dst, int n,
                                   const int* __restrict__ flag) {
  int f = *flag;
  for (int i = blockIdx.x * blockDim.x + threadIdx.x; i < n; i += gridDim.x * blockDim.x)
    dst[i] = f ? ((const float*)src)[i] : b2f(((const unsigned short*)src)[i]);
}

__global__ void signal_kernel(float* out) { if (threadIdx.x == 0) out[0] = 999.0f; }

// ---------------- GEMM: C[M,N] = A[M,K] @ W[N,K]^T + bias, bf16 in, fp32 acc
// m97-style: global_load_lds width-16 staging, unpadded [128][32] LDS tiles.
__device__ __forceinline__ void gemm_bt_body(
    const unsigned short* __restrict__ A,
    const unsigned short* __restrict__ W,
    const unsigned short* __restrict__ bias,
    unsigned short* __restrict__ Cb, float* __restrict__ Cf, int fmt, int vmode,
    int K, int N, int bx, int by)
{
  const int BK = 32;
  __shared__ unsigned short As[128 * 32];
  __shared__ unsigned short Bs[128 * 32];
  const int t = threadIdx.x;
  const int wave = t >> 6, lane = t & 63;
  const int quad = lane >> 4, l16 = lane & 15;
  const int m0 = by * 128, n0 = bx * 128;
  const int wm = (wave >> 1) * 64, wn = (wave & 1) * 64;

  f32x4 acc[4][4] = {};

  // staging: thread t covers 16B block (row = t>>2, blk = t&3) in rows 0..63
  // and the same in rows 64..127. LDS dst is lane-linear: As + t*8 elems.
  const int srow = t >> 2, sblk = t & 3;
  const unsigned short* Ag1 = A + (size_t)(m0 + srow) * K + sblk * 8;
  const unsigned short* Ag2 = A + (size_t)(m0 + 64 + srow) * K + sblk * 8;
  const unsigned short* Wg1 = W + (size_t)(n0 + srow) * K + sblk * 8;
  const unsigned short* Wg2 = W + (size_t)(n0 + 64 + srow) * K + sblk * 8;
  unsigned short* As1 = &As[t * 8];
  unsigned short* As2 = &As[2048 + t * 8];
  unsigned short* Bs1 = &Bs[t * 8];
  unsigned short* Bs2 = &Bs[2048 + t * 8];

  for (int k0 = 0; k0 < K; k0 += BK) {
    __syncthreads();                 // prev iter's reads done
    gll16(Ag1 + k0, As1);
    gll16(Ag2 + k0, As2);
    gll16(Wg1 + k0, Bs1);
    gll16(Wg2 + k0, Bs2);
    __syncthreads();                 // drains vmcnt (gll complete) + visibility
    bf16x8 af[4], bfr[4];
#pragma unroll
    for (int i = 0; i < 4; ++i)
      af[i] = *(const bf16x8*)&As[(wm + i * 16 + l16) * 32 + quad * 8];
#pragma unroll
    for (int j = 0; j < 4; ++j)
      bfr[j] = *(const bf16x8*)&Bs[(wn + j * 16 + l16) * 32 + quad * 8];
#pragma unroll
    for (int i = 0; i < 4; ++i)
#pragma unroll
      for (int j = 0; j < 4; ++j)
        acc[i][j] = __builtin_amdgcn_mfma_f32_16x16x32_bf16(af[i], bfr[j], acc[i][j], 0, 0, 0);
  }

#pragma unroll
  for (int i = 0; i < 4; ++i) {
    int row = m0 + wm + i * 16 + quad * 4;
#pragma unroll
    for (int j = 0; j < 4; ++j) {
      int col = n0 + wn + j * 16 + l16;
      float bv = b2f(bias[col]);
      if (vmode) {  // transposed: vt[col][row..row+3], 8B packed store
        union { unsigned short h4[4]; uint2 u; } pk;
#pragma unroll
        for (int r = 0; r < 4; ++r) pk.h4[r] = f2b(acc[i][j][r] + bv);
        *(uint2*)&Cb[(size_t)col * SEQ + row] = pk.u;
      } else {
#pragma unroll
        for (int r = 0; r < 4; ++r) {
          float v = acc[i][j][r] + bv;
          size_t idx = (size_t)(row + r) * N + col;
          if (fmt) Cf[idx] = v; else Cb[idx] = f2b(v);
        }
      }
    }
  }
}

__global__ __launch_bounds__(256) void qkv_gemm_kernel(
    const unsigned short* __restrict__ x,
    const unsigned short* __restrict__ Wq, const unsigned short* __restrict__ bq,
    const unsigned short* __restrict__ Wk, const unsigned short* __restrict__ bk,
    const unsigned short* __restrict__ Wv, const unsigned short* __restrict__ bv,
    unsigned short* qb, unsigned short* kb, unsigned short* vt)
{
  const unsigned short *W, *b; unsigned short* C; int vm = 0;
  if (blockIdx.z == 0)      { W = Wq; b = bq; C = qb; }
  else if (blockIdx.z == 1) { W = Wk; b = bk; C = kb; }
  else                      { W = Wv; b = bv; C = vt; vm = 1; }
  gemm_bt_body(x, W, b, C, nullptr, 0, vm, DIM, DIM, blockIdx.x, blockIdx.y);
}

__global__ __launch_bounds__(256) void out_gemm_kernel(
    const unsigned short* __restrict__ ab, const unsigned short* __restrict__ Wo,
    const unsigned short* __restrict__ bo, void* out, const int* __restrict__ flag)
{
  int fmt = *flag;
  gemm_bt_body(ab, Wo, bo, (unsigned short*)out, (float*)out, fmt, 0,
               DIM, DIM, blockIdx.x, blockIdx.y);
}

// ---------------- RMSNorm + RoPE, in place; q additionally pre-scaled 1/sqrt(d)
__global__ __launch_bounds__(256) void norm_rope_kernel(
    unsigned short* __restrict__ qb, unsigned short* __restrict__ kb,
    const unsigned short* __restrict__ gq, const unsigned short* __restrict__ gk,
    const float* __restrict__ freqsf)
{
  const int s = blockIdx.x;
  const int isq = (blockIdx.y == 0);
  unsigned short* row = (isq ? qb : kb) + (size_t)s * DIM;
  const unsigned short* g = (isq ? gq : gk);
  const int t = threadIdx.x;
  float ss = 0.f;
#pragma unroll
  for (int i = 0; i < 6; ++i) {
    float xv = b2f(row[t + 256 * i]);
    ss += xv * xv;
  }
#pragma unroll
  for (int off = 32; off > 0; off >>= 1) ss += __shfl_down(ss, off);
  __shared__ float red[4];
  if ((t & 63) == 0) red[t >> 6] = ss;
  __syncthreads();
  float tot = red[0] + red[1] + red[2] + red[3];
  float rinv = 1.0f / sqrtf(tot * (1.0f / DIM) + 1e-6f);
  if (isq) rinv *= 0.08838834764831845f;   // fold 1/sqrt(128) into q
#pragma unroll
  for (int i = 0; i < 3; ++i) {
    int pg = t + 256 * i;
    int c0 = pg * 2;
    float x0 = b2f(row[c0]), x1 = b2f(row[c0 + 1]);
    float y0 = x0 * rinv * b2f(g[c0]);
    float y1 = x1 * rinv * b2f(g[c0 + 1]);
    float ang = freqsf[s * 64 + (pg & 63)];
    float sn, cs;
    __sincosf(ang, &sn, &cs);
    row[c0]     = f2b(y0 * cs - y1 * sn);
    row[c0 + 1] = f2b(y0 * sn + y1 * cs);
  }
}

// ---------------- Flash attention: 128 q/block, key-split x2, reg-prefetch dbuf
#define LDPS 72   // Ps row stride

__global__ __launch_bounds__(256) void attn_kernel(
    const unsigned short* __restrict__ qb,
    const unsigned short* __restrict__ kb,
    const unsigned short* __restrict__ vt,   // [DIM][SEQ] transposed V
    float* __restrict__ op,                  // [2][SEQ][DIM] partial O
    float* __restrict__ lp)                  // [2][HEADS][SEQ] partial L
{
  __shared__ unsigned short Ks[64 * 128];      // [key][d], swizzled
  __shared__ unsigned short Vs[128 * 64];      // [d][key], swizzled
  __shared__ __bf16 Ps[4][32 * LDPS];          // per-wave P [32 q][64 key]

  const int t = threadIdx.x;
  const int wave = t >> 6, lane = t & 63;
  const int quad = lane >> 4, l16 = lane & 15;
  const int h = blockIdx.y;
  const int z = blockIdx.z;
  const int qbase = blockIdx.x * 128 + wave * 32;   // 32 q rows per wave
  const int kc0 = z * (SEQ / 2);

  // Q A-frags: 2 m-tiles x 4 k-groups
  bf16x8 qf[2][4];
#pragma unroll
  for (int mt = 0; mt < 2; ++mt)
#pragma unroll
    for (int kk = 0; kk < 4; ++kk)
      qf[mt][kk] = *(const bf16x8*)(qb + (size_t)(qbase + mt * 16 + l16) * DIM
                                    + h * HD + kk * 32 + quad * 8);

  f32x4 o[2][8] = {};
  float Lr[2][4] = {};

  const int krow = t >> 2, kblk = (t & 3) * 4;   // K stage: 4x16B per thread
  const int vd = t >> 1,  vblk = (t & 1) * 4;    // V stage: 4x16B per thread

  // prefetch registers for next chunk's K/V
  uint4 ka[4], va[4];
  {
    const unsigned short* src = kb + (size_t)(kc0 + krow) * DIM + h * HD + kblk * 8;
    ka[0] = *(const uint4*)(src);      ka[1] = *(const uint4*)(src + 8);
    ka[2] = *(const uint4*)(src + 16); ka[3] = *(const uint4*)(src + 24);
    const unsigned short* sv = vt + ((size_t)h * HD + vd) * SEQ + kc0 + vblk * 8;
    va[0] = *(const uint4*)(sv);       va[1] = *(const uint4*)(sv + 8);
    va[2] = *(const uint4*)(sv + 16);  va[3] = *(const uint4*)(sv + 24);
  }

  for (int kc = kc0; kc < kc0 + SEQ / 2; kc += 64) {
    __syncthreads();                       // readers of previous chunk done
    {  // staged regs -> LDS (swizzled)
      unsigned short* dst = &Ks[krow * 128];
      const int sw = krow & 7;
      *(uint4*)(dst + ((kblk + 0) ^ sw) * 8) = ka[0];
      *(uint4*)(dst + ((kblk + 1) ^ sw) * 8) = ka[1];
      *(uint4*)(dst + ((kblk + 2) ^ sw) * 8) = ka[2];
      *(uint4*)(dst + ((kblk + 3) ^ sw) * 8) = ka[3];
      unsigned short* dv = &Vs[vd * 64];
      const int swv = vd & 7;
      *(uint4*)(dv + ((vblk + 0) ^ swv) * 8) = va[0];
      *(uint4*)(dv + ((vblk + 1) ^ swv) * 8) = va[1];
      *(uint4*)(dv + ((vblk + 2) ^ swv) * 8) = va[2];
      *(uint4*)(dv + ((vblk + 3) ^ swv) * 8) = va[3];
    }
    __syncthreads();

    // issue next chunk's global loads; waited only at next LDS-write
    if (kc + 64 < kc0 + SEQ / 2) {
      const unsigned short* src = kb + (size_t)(kc + 64 + krow) * DIM + h * HD + kblk * 8;
      ka[0] = *(const uint4*)(src);      ka[1] = *(const uint4*)(src + 8);
      ka[2] = *(const uint4*)(src + 16); ka[3] = *(const uint4*)(src + 24);
      const unsigned short* sv = vt + ((size_t)h * HD + vd) * SEQ + kc + 64 + vblk * 8;
      va[0] = *(const uint4*)(sv);       va[1] = *(const uint4*)(sv + 8);
      va[2] = *(const uint4*)(sv + 16);  va[3] = *(const uint4*)(sv + 24);
    }

    // S = Q @ K^T : each kf read feeds both m-tiles
    f32x4 sc[2][4] = {};
#pragma unroll
    for (int kk = 0; kk < 4; ++kk) {
#pragma unroll
      for (int j = 0; j < 4; ++j) {
        int row = j * 16 + l16;
        bf16x8 kf = *(const bf16x8*)&Ks[row * 128 + ((kk * 4 + quad) ^ (row & 7)) * 8];
        sc[0][j] = __builtin_amdgcn_mfma_f32_16x16x32_bf16(qf[0][kk], kf, sc[0][j], 0, 0, 0);
        sc[1][j] = __builtin_amdgcn_mfma_f32_16x16x32_bf16(qf[1][kk], kf, sc[1][j], 0, 0, 0);
      }
    }

    // fixed-max softmax (scores bounded: q,k RMS-normalized)
#pragma unroll
    for (int mt = 0; mt < 2; ++mt)
#pragma unroll
      for (int j = 0; j < 4; ++j)
#pragma unroll
        for (int r = 0; r < 4; ++r) {
          float p = __expf(sc[mt][j][r]);
          Lr[mt][r] += p;
          Ps[wave][(mt * 16 + quad * 4 + r) * LDPS + j * 16 + l16] = (__bf16)p;
        }

    __asm__ __volatile__("" ::: "memory");

    // O += P @ V : each vf read feeds both m-tiles
#pragma unroll
    for (int kk2 = 0; kk2 < 2; ++kk2) {
      bf16x8 pf0 = *(const bf16x8*)&Ps[wave][(0 * 16 + l16) * LDPS + kk2 * 32 + quad * 8];
      bf16x8 pf1 = *(const bf16x8*)&Ps[wave][(1 * 16 + l16) * LDPS + kk2 * 32 + quad * 8];
#pragma unroll
      for (int j2 = 0; j2 < 8; ++j2) {
        bf16x8 vf = *(const bf16x8*)&Vs[(j2 * 16 + l16) * 64
                                        + ((kk2 * 4 + quad) ^ (l16 & 7)) * 8];
        o[0][j2] = __builtin_amdgcn_mfma_f32_16x16x32_bf16(pf0, vf, o[0][j2], 0, 0, 0);
        o[1][j2] = __builtin_amdgcn_mfma_f32_16x16x32_bf16(pf1, vf, o[1][j2], 0, 0, 0);
      }
    }
  }

  // write partial L (one lane per row) and partial O (fp32, unnormalized)
  float* opz = op + (size_t)z * SEQ * DIM;
  float* lpz = lp + (size_t)z * HEADS * SEQ + (size_t)h * SEQ;
#pragma unroll
  for (int mt = 0; mt < 2; ++mt) {
#pragma unroll
    for (int r = 0; r < 4; ++r) {
      float L = Lr[mt][r];
#pragma unroll
      for (int off = 1; off < 16; off <<= 1) L += __shfl_xor(L, off);
      if (l16 == 0) lpz[qbase + mt * 16 + quad * 4 + r] = L;
    }
#pragma unroll
    for (int j2 = 0; j2 < 8; ++j2) {
      int col = h * HD + j2 * 16 + l16;
#pragma unroll
      for (int r = 0; r < 4; ++r) {
        int row = qbase + mt * 16 + quad * 4 + r;
        opz[(size_t)row * DIM + col] = o[mt][j2][r];
      }
    }
  }
}

// combine the two key-halves: ab = (O0+O1) / (L0+L1), cast to bf16
__global__ __launch_bounds__(256) void combine_kernel(
    const float* __restrict__ op, const float* __restrict__ lp,
    unsigned short* __restrict__ ab)
{
  int idx = blockIdx.x * 256 + threadIdx.x;       // over SEQ*DIM
  int row = idx / DIM, col = idx - row * DIM;
  int h = col >> 7;
  float o = op[idx] + op[(size_t)SEQ * DIM + idx];
  float l = lp[(size_t)h * SEQ + row] + lp[(size_t)(HEADS + h) * SEQ + row];
  ab[idx] = f2b(o / l);
}

extern "C" void kernel_launch(void* const* d_in, const int* in_sizes, int n_in,
                              void* d_out, int out_size, void* d_ws, size_t ws_size,
                              hipStream_t stream) {
  const int NX = SEQ * DIM, NW = DIM * DIM, NB = DIM, NF = SEQ * 64;

  char* w = (char*)d_ws;
  size_t off = 0;
  int* flag = (int*)(w + off);              off += 256;
  unsigned short* xb  = (unsigned short*)(w + off); off += (size_t)NX * 2;
  unsigned short* Wqb = (unsigned short*)(w + off); off += (size_t)NW * 2;
  unsigned short* Wkb = (unsigned short*)(w + off); off += (size_t)NW * 2;
  unsigned short* Wvb = (unsigned short*)(w + off); off += (size_t)NW * 2;
  unsigned short* Wob = (unsigned short*)(w + off); off += (size_t)NW * 2;
  unsigned short* bqb = (unsigned short*)(w + off); off += 4096;
  unsigned short* bkb = (unsigned short*)(w + off); off += 4096;
  unsigned short* bvb = (unsigned short*)(w + off); off += 4096;
  unsigned short* bob = (unsigned short*)(w + off); off += 4096;
  unsigned short* gqb = (unsigned short*)(w + off); off += 4096;
  unsigned short* gkb = (unsigned short*)(w + off); off += 4096;
  float* freqsf = (float*)(w + off);        off += (size_t)NF * 4;
  unsigned short* qb = (unsigned short*)(w + off); off += (size_t)NX * 2;
  unsigned short* kb = (unsigned short*)(w + off); off += (size_t)NX * 2;
  unsigned short* vt = (unsigned short*)(w + off); off += (size_t)NX * 2;
  unsigned short* ab = (unsigned short*)(w + off); off += (size_t)NX * 2;
  float* op = (float*)(w + off);            off += (size_t)2 * NX * 4;  // partial O
  float* lp = (float*)(w + off);            off += (size_t)2 * HEADS * SEQ * 4;

  if (ws_size < off) {
    signal_kernel<<<1, 64, 0, stream>>>((float*)d_out);
    return;
  }

  detect_kernel<<<1, 256, 0, stream>>>((const unsigned int*)d_in[0], flag);

  const int CT = 256;
  auto cgrid = [](int n) { int g = (n + 255) / 256; return g > 4096 ? 4096 : g; };
  convert_bf16_kernel<<<cgrid(NX), CT, 0, stream>>>(d_in[0], xb, NX, flag);
  convert_w4_kernel<<<dim3(cgrid(NW), 4), CT, 0, stream>>>(
      d_in[2], d_in[4], d_in[6], d_in[8], Wqb, Wkb, Wvb, Wob, NW, flag);
  convert_v6_kernel<<<dim3(cgrid(NB), 6), CT, 0, stream>>>(
      d_in[3], d_in[5], d_in[7], d_in[9], d_in[10], d_in[11],
      bqb, bkb, bvb, bob, gqb, gkb, NB, flag);
  convert_f32_kernel<<<cgrid(NF), CT, 0, stream>>>(d_in[1], freqsf, NF, flag);

  qkv_gemm_kernel<<<dim3(DIM / 128, SEQ / 128, 3), 256, 0, stream>>>(
      xb, Wqb, bqb, Wkb, bkb, Wvb, bvb, qb, kb, vt);
  norm_rope_kernel<<<dim3(SEQ, 2), 256, 0, stream>>>(qb, kb, gqb, gkb, freqsf);
  attn_kernel<<<dim3(SEQ / 128, HEADS, 2), 256, 0, stream>>>(qb, kb, vt, op, lp);
  combine_kernel<<<NX / 256, 256, 0, stream>>>(op, lp, ab);
  out_gemm_kernel<<<dim3(DIM / 128, SEQ / 128), 256, 0, stream>>>(ab, Wob, bob, d_out, flag);
}

// Round 8
// 484.042 us; speedup vs baseline: 1.2669x; 1.2669x over previous
//
#include <hip/hip_runtime.h>
#include <stdint.h>
#include <math.h>

#define DIM 1536
#define SEQ 4096
#define HEADS 12
#define HD 128

typedef __bf16 bf16x8 __attribute__((ext_vector_type(8)));
typedef float f32x4 __attribute__((ext_vector_type(4)));

typedef __attribute__((address_space(1))) void gas_void;
typedef __attribute__((address_space(3))) void las_void;

__device__ __forceinline__ float b2f(unsigned short u) {
  union { unsigned int i; float f; } x; x.i = ((unsigned int)u) << 16; return x.f;
}
__device__ __forceinline__ unsigned short f2b(float f) {
  union { float f; unsigned int i; } x; x.f = f;
  unsigned int u = x.i;
  unsigned int r = (u + 0x7fffu + ((u >> 16) & 1u)) >> 16;  // RNE
  return (unsigned short)r;
}
// async global->LDS 16B: LDS placement is wave-uniform base + lane*16
__device__ __forceinline__ void gll16(const unsigned short* g, unsigned short* l) {
  __builtin_amdgcn_global_load_lds((gas_void*)g, (las_void*)l, 16, 0, 0);
}

// ---------------- dtype detector: flag=0 bf16 inputs, flag=1 fp32 inputs
__global__ void detect_kernel(const unsigned int* __restrict__ xw, int* flag) {
  __shared__ int cnt;
  if (threadIdx.x == 0) cnt = 0;
  __syncthreads();
  int local = 0;
  for (int i = threadIdx.x; i < 1024; i += 256) {
    unsigned int e = (xw[i] >> 7) & 0xFFu;
    if (e >= 110u && e <= 140u) local++;
  }
  atomicAdd(&cnt, local);
  __syncthreads();
  if (threadIdx.x == 0) *flag = (cnt > 512) ? 0 : 1;
}

__global__ void convert_bf16_kernel(const void* __restrict__ src,
                                    unsigned short* __restrict__ dst, int n,
                                    const int* __restrict__ flag) {
  int f = *flag;
  for (int i = blockIdx.x * blockDim.x + threadIdx.x; i < n; i += gridDim.x * blockDim.x)
    dst[i] = f ? f2b(((const float*)src)[i]) : ((const unsigned short*)src)[i];
}

__global__ void convert_w4_kernel(const void* s0, const void* s1, const void* s2, const void* s3,
                                  unsigned short* d0, unsigned short* d1,
                                  unsigned short* d2, unsigned short* d3,
                                  int n, const int* __restrict__ flag) {
  const void* s; unsigned short* d;
  switch (blockIdx.y) {
    case 0: s = s0; d = d0; break;
    case 1: s = s1; d = d1; break;
    case 2: s = s2; d = d2; break;
    default: s = s3; d = d3; break;
  }
  int f = *flag;
  for (int i = blockIdx.x * blockDim.x + threadIdx.x; i < n; i += gridDim.x * blockDim.x)
    d[i] = f ? f2b(((const float*)s)[i]) : ((const unsigned short*)s)[i];
}

__global__ void convert_v6_kernel(const void* s0, const void* s1, const void* s2,
                                  const void* s3, const void* s4, const void* s5,
                                  unsigned short* d0, unsigned short* d1, unsigned short* d2,
                                  unsigned short* d3, unsigned short* d4, unsigned short* d5,
                                  int n, const int* __restrict__ flag) {
  const void* s; unsigned short* d;
  switch (blockIdx.y) {
    case 0: s = s0; d = d0; break;
    case 1: s = s1; d = d1; break;
    case 2: s = s2; d = d2; break;
    case 3: s = s3; d = d3; break;
    case 4: s = s4; d = d4; break;
    default: s = s5; d = d5; break;
  }
  int f = *flag;
  for (int i = blockIdx.x * blockDim.x + threadIdx.x; i < n; i += gridDim.x * blockDim.x)
    d[i] = f ? f2b(((const float*)s)[i]) : ((const unsigned short*)s)[i];
}

__global__ void convert_f32_kernel(const void* __restrict__ src,
                                   float* __restrict__ dst, int n,
                                   const int* __restrict__ flag) {
  int f = *flag;
  for (int i = blockIdx.x * blockDim.x + threadIdx.x; i < n; i += gridDim.x * blockDim.x)
    dst[i] = f ? ((const float*)src)[i] : b2f(((const unsigned short*)src)[i]);
}

__global__ void signal_kernel(float* out) { if (threadIdx.x == 0) out[0] = 999.0f; }

// ---------------- GEMM: C[M,N] = A[M,K] @ W[N,K]^T + bias, bf16 in, fp32 acc
// m97-style: global_load_lds width-16 staging, unpadded [128][32] LDS tiles.
__device__ __forceinline__ void gemm_bt_body(
    const unsigned short* __restrict__ A,
    const unsigned short* __restrict__ W,
    const unsigned short* __restrict__ bias,
    unsigned short* __restrict__ Cb, float* __restrict__ Cf, int fmt, int vmode,
    int K, int N, int bx, int by)
{
  const int BK = 32;
  __shared__ unsigned short As[128 * 32];
  __shared__ unsigned short Bs[128 * 32];
  const int t = threadIdx.x;
  const int wave = t >> 6, lane = t & 63;
  const int quad = lane >> 4, l16 = lane & 15;
  const int m0 = by * 128, n0 = bx * 128;
  const int wm = (wave >> 1) * 64, wn = (wave & 1) * 64;

  f32x4 acc[4][4] = {};

  const int srow = t >> 2, sblk = t & 3;
  const unsigned short* Ag1 = A + (size_t)(m0 + srow) * K + sblk * 8;
  const unsigned short* Ag2 = A + (size_t)(m0 + 64 + srow) * K + sblk * 8;
  const unsigned short* Wg1 = W + (size_t)(n0 + srow) * K + sblk * 8;
  const unsigned short* Wg2 = W + (size_t)(n0 + 64 + srow) * K + sblk * 8;
  unsigned short* As1 = &As[t * 8];
  unsigned short* As2 = &As[2048 + t * 8];
  unsigned short* Bs1 = &Bs[t * 8];
  unsigned short* Bs2 = &Bs[2048 + t * 8];

  for (int k0 = 0; k0 < K; k0 += BK) {
    __syncthreads();                 // prev iter's reads done
    gll16(Ag1 + k0, As1);
    gll16(Ag2 + k0, As2);
    gll16(Wg1 + k0, Bs1);
    gll16(Wg2 + k0, Bs2);
    __syncthreads();                 // drains vmcnt (gll complete) + visibility
    bf16x8 af[4], bfr[4];
#pragma unroll
    for (int i = 0; i < 4; ++i)
      af[i] = *(const bf16x8*)&As[(wm + i * 16 + l16) * 32 + quad * 8];
#pragma unroll
    for (int j = 0; j < 4; ++j)
      bfr[j] = *(const bf16x8*)&Bs[(wn + j * 16 + l16) * 32 + quad * 8];
#pragma unroll
    for (int i = 0; i < 4; ++i)
#pragma unroll
      for (int j = 0; j < 4; ++j)
        acc[i][j] = __builtin_amdgcn_mfma_f32_16x16x32_bf16(af[i], bfr[j], acc[i][j], 0, 0, 0);
  }

#pragma unroll
  for (int i = 0; i < 4; ++i) {
    int row = m0 + wm + i * 16 + quad * 4;
#pragma unroll
    for (int j = 0; j < 4; ++j) {
      int col = n0 + wn + j * 16 + l16;
      float bv = b2f(bias[col]);
      if (vmode) {  // transposed: vt[col][row..row+3], 8B packed store
        union { unsigned short h4[4]; uint2 u; } pk;
#pragma unroll
        for (int r = 0; r < 4; ++r) pk.h4[r] = f2b(acc[i][j][r] + bv);
        *(uint2*)&Cb[(size_t)col * SEQ + row] = pk.u;
      } else {
#pragma unroll
        for (int r = 0; r < 4; ++r) {
          float v = acc[i][j][r] + bv;
          size_t idx = (size_t)(row + r) * N + col;
          if (fmt) Cf[idx] = v; else Cb[idx] = f2b(v);
        }
      }
    }
  }
}

__global__ __launch_bounds__(256) void qkv_gemm_kernel(
    const unsigned short* __restrict__ x,
    const unsigned short* __restrict__ Wq, const unsigned short* __restrict__ bq,
    const unsigned short* __restrict__ Wk, const unsigned short* __restrict__ bk,
    const unsigned short* __restrict__ Wv, const unsigned short* __restrict__ bv,
    unsigned short* qb, unsigned short* kb, unsigned short* vt)
{
  const unsigned short *W, *b; unsigned short* C; int vm = 0;
  if (blockIdx.z == 0)      { W = Wq; b = bq; C = qb; }
  else if (blockIdx.z == 1) { W = Wk; b = bk; C = kb; }
  else                      { W = Wv; b = bv; C = vt; vm = 1; }
  gemm_bt_body(x, W, b, C, nullptr, 0, vm, DIM, DIM, blockIdx.x, blockIdx.y);
}

__global__ __launch_bounds__(256) void out_gemm_kernel(
    const unsigned short* __restrict__ ab, const unsigned short* __restrict__ Wo,
    const unsigned short* __restrict__ bo, void* out, const int* __restrict__ flag)
{
  int fmt = *flag;
  gemm_bt_body(ab, Wo, bo, (unsigned short*)out, (float*)out, fmt, 0,
               DIM, DIM, blockIdx.x, blockIdx.y);
}

// ---------------- RMSNorm + RoPE, in place; q additionally pre-scaled 1/sqrt(d)
__global__ __launch_bounds__(256) void norm_rope_kernel(
    unsigned short* __restrict__ qb, unsigned short* __restrict__ kb,
    const unsigned short* __restrict__ gq, const unsigned short* __restrict__ gk,
    const float* __restrict__ freqsf)
{
  const int s = blockIdx.x;
  const int isq = (blockIdx.y == 0);
  unsigned short* row = (isq ? qb : kb) + (size_t)s * DIM;
  const unsigned short* g = (isq ? gq : gk);
  const int t = threadIdx.x;
  float ss = 0.f;
#pragma unroll
  for (int i = 0; i < 6; ++i) {
    float xv = b2f(row[t + 256 * i]);
    ss += xv * xv;
  }
#pragma unroll
  for (int off = 32; off > 0; off >>= 1) ss += __shfl_down(ss, off);
  __shared__ float red[4];
  if ((t & 63) == 0) red[t >> 6] = ss;
  __syncthreads();
  float tot = red[0] + red[1] + red[2] + red[3];
  float rinv = 1.0f / sqrtf(tot * (1.0f / DIM) + 1e-6f);
  if (isq) rinv *= 0.08838834764831845f;   // fold 1/sqrt(128) into q
#pragma unroll
  for (int i = 0; i < 3; ++i) {
    int pg = t + 256 * i;
    int c0 = pg * 2;
    float x0 = b2f(row[c0]), x1 = b2f(row[c0 + 1]);
    float y0 = x0 * rinv * b2f(g[c0]);
    float y1 = x1 * rinv * b2f(g[c0 + 1]);
    float ang = freqsf[s * 64 + (pg & 63)];
    float sn, cs;
    __sincosf(ang, &sn, &cs);
    row[c0]     = f2b(y0 * cs - y1 * sn);
    row[c0 + 1] = f2b(y0 * sn + y1 * cs);
  }
}

// ---------------- Flash attention: 128 q/block, additive key-split (grid.z)
#define LDPS 72   // Ps row stride

__global__ __launch_bounds__(256) void attn_kernel(
    const unsigned short* __restrict__ qb,
    const unsigned short* __restrict__ kb,
    const unsigned short* __restrict__ vt,   // [DIM][SEQ] transposed V
    float* __restrict__ op,                  // [nz][SEQ][DIM] partial O
    float* __restrict__ lp,                  // [nz][HEADS][SEQ] partial L
    int seg)                                 // keys per z-slice (SEQ/nz)
{
  __shared__ unsigned short Ks[64 * 128];      // [key][d], swizzled
  __shared__ unsigned short Vs[128 * 64];      // [d][key], swizzled
  __shared__ __bf16 Ps[4][32 * LDPS];          // per-wave P [32 q][64 key]

  const int t = threadIdx.x;
  const int wave = t >> 6, lane = t & 63;
  const int quad = lane >> 4, l16 = lane & 15;
  const int h = blockIdx.y;
  const int z = blockIdx.z;
  const int qbase = blockIdx.x * 128 + wave * 32;   // 32 q rows per wave
  const int kc0 = z * seg;

  // Q A-frags: 2 m-tiles x 4 k-groups
  bf16x8 qf[2][4];
#pragma unroll
  for (int mt = 0; mt < 2; ++mt)
#pragma unroll
    for (int kk = 0; kk < 4; ++kk)
      qf[mt][kk] = *(const bf16x8*)(qb + (size_t)(qbase + mt * 16 + l16) * DIM
                                    + h * HD + kk * 32 + quad * 8);

  f32x4 o[2][8] = {};
  float Lr[2][4] = {};

  const int krow = t >> 2, kblk = (t & 3) * 4;   // K stage: 4x16B per thread
  const int vd = t >> 1,  vblk = (t & 1) * 4;    // V stage: 4x16B per thread

  for (int kc = kc0; kc < kc0 + seg; kc += 64) {
    __syncthreads();
    {  // stage K [64][128] with block swizzle
      const unsigned short* src = kb + (size_t)(kc + krow) * DIM + h * HD + kblk * 8;
      uint4 u0 = *(const uint4*)(src);
      uint4 u1 = *(const uint4*)(src + 8);
      uint4 u2 = *(const uint4*)(src + 16);
      uint4 u3 = *(const uint4*)(src + 24);
      unsigned short* dst = &Ks[krow * 128];
      const int sw = krow & 7;
      *(uint4*)(dst + ((kblk + 0) ^ sw) * 8) = u0;
      *(uint4*)(dst + ((kblk + 1) ^ sw) * 8) = u1;
      *(uint4*)(dst + ((kblk + 2) ^ sw) * 8) = u2;
      *(uint4*)(dst + ((kblk + 3) ^ sw) * 8) = u3;
    }
    {  // stage V [128 d][64 key] from pre-transposed vt, block swizzle
      const unsigned short* src = vt + ((size_t)h * HD + vd) * SEQ + kc + vblk * 8;
      uint4 u0 = *(const uint4*)(src);
      uint4 u1 = *(const uint4*)(src + 8);
      uint4 u2 = *(const uint4*)(src + 16);
      uint4 u3 = *(const uint4*)(src + 24);
      unsigned short* dst = &Vs[vd * 64];
      const int sw = vd & 7;
      *(uint4*)(dst + ((vblk + 0) ^ sw) * 8) = u0;
      *(uint4*)(dst + ((vblk + 1) ^ sw) * 8) = u1;
      *(uint4*)(dst + ((vblk + 2) ^ sw) * 8) = u2;
      *(uint4*)(dst + ((vblk + 3) ^ sw) * 8) = u3;
    }
    __syncthreads();

    // S = Q @ K^T : each kf read feeds both m-tiles
    f32x4 sc[2][4] = {};
#pragma unroll
    for (int kk = 0; kk < 4; ++kk) {
#pragma unroll
      for (int j = 0; j < 4; ++j) {
        int row = j * 16 + l16;
        bf16x8 kf = *(const bf16x8*)&Ks[row * 128 + ((kk * 4 + quad) ^ (row & 7)) * 8];
        sc[0][j] = __builtin_amdgcn_mfma_f32_16x16x32_bf16(qf[0][kk], kf, sc[0][j], 0, 0, 0);
        sc[1][j] = __builtin_amdgcn_mfma_f32_16x16x32_bf16(qf[1][kk], kf, sc[1][j], 0, 0, 0);
      }
    }

    // fixed-max softmax (scores bounded: q,k RMS-normalized)
#pragma unroll
    for (int mt = 0; mt < 2; ++mt)
#pragma unroll
      for (int j = 0; j < 4; ++j)
#pragma unroll
        for (int r = 0; r < 4; ++r) {
          float p = __expf(sc[mt][j][r]);
          Lr[mt][r] += p;
          Ps[wave][(mt * 16 + quad * 4 + r) * LDPS + j * 16 + l16] = (__bf16)p;
        }

    __asm__ __volatile__("" ::: "memory");

    // O += P @ V : each vf read feeds both m-tiles
#pragma unroll
    for (int kk2 = 0; kk2 < 2; ++kk2) {
      bf16x8 pf0 = *(const bf16x8*)&Ps[wave][(0 * 16 + l16) * LDPS + kk2 * 32 + quad * 8];
      bf16x8 pf1 = *(const bf16x8*)&Ps[wave][(1 * 16 + l16) * LDPS + kk2 * 32 + quad * 8];
#pragma unroll
      for (int j2 = 0; j2 < 8; ++j2) {
        bf16x8 vf = *(const bf16x8*)&Vs[(j2 * 16 + l16) * 64
                                        + ((kk2 * 4 + quad) ^ (l16 & 7)) * 8];
        o[0][j2] = __builtin_amdgcn_mfma_f32_16x16x32_bf16(pf0, vf, o[0][j2], 0, 0, 0);
        o[1][j2] = __builtin_amdgcn_mfma_f32_16x16x32_bf16(pf1, vf, o[1][j2], 0, 0, 0);
      }
    }
  }

  // write partial L (one lane per row) and partial O (fp32, unnormalized)
  float* opz = op + (size_t)z * SEQ * DIM;
  float* lpz = lp + (size_t)z * HEADS * SEQ + (size_t)h * SEQ;
#pragma unroll
  for (int mt = 0; mt < 2; ++mt) {
#pragma unroll
    for (int r = 0; r < 4; ++r) {
      float L = Lr[mt][r];
#pragma unroll
      for (int off = 1; off < 16; off <<= 1) L += __shfl_xor(L, off);
      if (l16 == 0) lpz[qbase + mt * 16 + quad * 4 + r] = L;
    }
#pragma unroll
    for (int j2 = 0; j2 < 8; ++j2) {
      int col = h * HD + j2 * 16 + l16;
#pragma unroll
      for (int r = 0; r < 4; ++r) {
        int row = qbase + mt * 16 + quad * 4 + r;
        opz[(size_t)row * DIM + col] = o[mt][j2][r];
      }
    }
  }
}

// combine nz key-slices: ab = (sum O_z) / (sum L_z), cast to bf16
__global__ __launch_bounds__(256) void combine_kernel(
    const float* __restrict__ op, const float* __restrict__ lp,
    unsigned short* __restrict__ ab, int nz)
{
  int idx = blockIdx.x * 256 + threadIdx.x;       // over SEQ*DIM
  int row = idx / DIM, col = idx - row * DIM;
  int h = col >> 7;
  float o = 0.f, l = 0.f;
  for (int z = 0; z < nz; ++z) {
    o += op[(size_t)z * SEQ * DIM + idx];
    l += lp[(size_t)z * HEADS * SEQ + (size_t)h * SEQ + row];
  }
  ab[idx] = f2b(o / l);
}

extern "C" void kernel_launch(void* const* d_in, const int* in_sizes, int n_in,
                              void* d_out, int out_size, void* d_ws, size_t ws_size,
                              hipStream_t stream) {
  const int NX = SEQ * DIM, NW = DIM * DIM, NB = DIM, NF = SEQ * 64;

  char* w = (char*)d_ws;
  size_t off = 0;
  int* flag = (int*)(w + off);              off += 256;
  unsigned short* xb  = (unsigned short*)(w + off); off += (size_t)NX * 2;
  unsigned short* Wqb = (unsigned short*)(w + off); off += (size_t)NW * 2;
  unsigned short* Wkb = (unsigned short*)(w + off); off += (size_t)NW * 2;
  unsigned short* Wvb = (unsigned short*)(w + off); off += (size_t)NW * 2;
  unsigned short* Wob = (unsigned short*)(w + off); off += (size_t)NW * 2;
  unsigned short* bqb = (unsigned short*)(w + off); off += 4096;
  unsigned short* bkb = (unsigned short*)(w + off); off += 4096;
  unsigned short* bvb = (unsigned short*)(w + off); off += 4096;
  unsigned short* bob = (unsigned short*)(w + off); off += 4096;
  unsigned short* gqb = (unsigned short*)(w + off); off += 4096;
  unsigned short* gkb = (unsigned short*)(w + off); off += 4096;
  float* freqsf = (float*)(w + off);        off += (size_t)NF * 4;
  unsigned short* qb = (unsigned short*)(w + off); off += (size_t)NX * 2;
  unsigned short* kb = (unsigned short*)(w + off); off += (size_t)NX * 2;
  unsigned short* vt = (unsigned short*)(w + off); off += (size_t)NX * 2;
  unsigned short* ab = (unsigned short*)(w + off); off += (size_t)NX * 2;
  float* op = (float*)(w + off);            // nz * NX floats
  float* lp;

  // pick key-split factor by available ws (host-side, deterministic)
  int nz = 4;
  size_t need4 = off + (size_t)4 * NX * 4 + (size_t)4 * HEADS * SEQ * 4;
  size_t need2 = off + (size_t)2 * NX * 4 + (size_t)2 * HEADS * SEQ * 4;
  size_t need;
  if (ws_size >= need4)      { nz = 4; need = need4; }
  else if (ws_size >= need2) { nz = 2; need = need2; }
  else {
    signal_kernel<<<1, 64, 0, stream>>>((float*)d_out);
    return;
  }
  lp = (float*)(w + off + (size_t)nz * NX * 4);

  detect_kernel<<<1, 256, 0, stream>>>((const unsigned int*)d_in[0], flag);

  const int CT = 256;
  auto cgrid = [](int n) { int g = (n + 255) / 256; return g > 4096 ? 4096 : g; };
  convert_bf16_kernel<<<cgrid(NX), CT, 0, stream>>>(d_in[0], xb, NX, flag);
  convert_w4_kernel<<<dim3(cgrid(NW), 4), CT, 0, stream>>>(
      d_in[2], d_in[4], d_in[6], d_in[8], Wqb, Wkb, Wvb, Wob, NW, flag);
  convert_v6_kernel<<<dim3(cgrid(NB), 6), CT, 0, stream>>>(
      d_in[3], d_in[5], d_in[7], d_in[9], d_in[10], d_in[11],
      bqb, bkb, bvb, bob, gqb, gkb, NB, flag);
  convert_f32_kernel<<<cgrid(NF), CT, 0, stream>>>(d_in[1], freqsf, NF, flag);

  qkv_gemm_kernel<<<dim3(DIM / 128, SEQ / 128, 3), 256, 0, stream>>>(
      xb, Wqb, bqb, Wkb, bkb, Wvb, bvb, qb, kb, vt);
  norm_rope_kernel<<<dim3(SEQ, 2), 256, 0, stream>>>(qb, kb, gqb, gkb, freqsf);
  attn_kernel<<<dim3(SEQ / 128, HEADS, nz), 256, 0, stream>>>(qb, kb, vt, op, lp, SEQ / nz);
  combine_kernel<<<NX / 256, 256, 0, stream>>>(op, lp, ab, nz);
  out_gemm_kernel<<<dim3(DIM / 128, SEQ / 128), 256, 0, stream>>>(ab, Wob, bob, d_out, flag);
}